// Round 4
// baseline (88.474 us; speedup 1.0000x reference)
//
#include <hip/hip_runtime.h>
#include <hip/hip_bf16.h>

#define NB 20000      // batch
#define KN 16         // neighbors
#define D 256
#define KDIM 512      // 2*D
#define MDIM 512      // 2*OUT stacked

typedef __bf16 bf16x8 __attribute__((ext_vector_type(8)));
typedef float f32x4 __attribute__((ext_vector_type(4)));

__device__ inline unsigned short f2bf(float f) {
    union { float f; unsigned int u; } a; a.f = f;
    unsigned int u = a.u;
    unsigned int r = (u + 0x7FFFu + ((u >> 16) & 1u)) >> 16;   // RNE
    return (unsigned short)r;
}

// --- kernel 1: W1||W2 f32 -> bf16, stacked [512][512] ---
__global__ __launch_bounds__(256) void convW_kernel(
        const float* __restrict__ W1, const float* __restrict__ W2,
        unsigned short* __restrict__ Wc) {
    int i = blockIdx.x * 256 + threadIdx.x;          // 65536 float4 chunks
    float4 v = (i < 32768) ? reinterpret_cast<const float4*>(W1)[i]
                           : reinterpret_cast<const float4*>(W2)[i - 32768];
    ushort4 o;
    o.x = f2bf(v.x); o.y = f2bf(v.y); o.z = f2bf(v.z); o.w = f2bf(v.w);
    reinterpret_cast<ushort4*>(Wc)[i] = o;
}

// --- kernel 2: gather + mean, MLP-maximized: all 17 row loads in flight ---
__global__ __launch_bounds__(256) void agg_kernel(
        const int* __restrict__ nodes, const int* __restrict__ neigh,
        const float* __restrict__ feat, unsigned short* __restrict__ comb) {
    int w = threadIdx.x >> 6;
    int lane = threadIdx.x & 63;
    int b = blockIdx.x * 4 + w;                      // grid = 5000 -> b < 20000
    const float4* f4 = reinterpret_cast<const float4*>(feat);  // row = 64 float4

    // preload all indices first (4x int4 = one 64B row of neigh)
    int node = nodes[b];
    int idx[KN];
    #pragma unroll
    for (int k = 0; k < KN; k += 4) {
        int4 q = *reinterpret_cast<const int4*>(&neigh[b * KN + k]);
        idx[k] = q.x; idx[k + 1] = q.y; idx[k + 2] = q.z; idx[k + 3] = q.w;
    }

    // issue ALL loads before any use: 17 float4 in registers (~68 VGPR)
    float4 s = f4[(size_t)node * 64 + lane];
    float4 v[KN];
    #pragma unroll
    for (int k = 0; k < KN; ++k)
        v[k] = f4[(size_t)idx[k] * 64 + lane];

    // pairwise tree reduction
    #pragma unroll
    for (int st = 8; st >= 1; st >>= 1)
        #pragma unroll
        for (int k = 0; k < st; ++k) {
            v[k].x += v[k + st].x; v[k].y += v[k + st].y;
            v[k].z += v[k + st].z; v[k].w += v[k + st].w;
        }
    const float inv = 1.0f / 16.0f;

    ushort4 sv; sv.x = f2bf(s.x); sv.y = f2bf(s.y); sv.z = f2bf(s.z); sv.w = f2bf(s.w);
    ushort4 mv; mv.x = f2bf(v[0].x * inv); mv.y = f2bf(v[0].y * inv);
    mv.z = f2bf(v[0].z * inv); mv.w = f2bf(v[0].w * inv);

    unsigned short* row = comb + (size_t)b * KDIM;
    *reinterpret_cast<ushort4*>(row + lane * 4) = sv;          // self  [0,256)
    *reinterpret_cast<ushort4*>(row + D + lane * 4) = mv;      // mean  [256,512)
}

// --- kernel 3: out[m][n] = relu(sum_k Wc[m][k] * comb[n][k]), f32 out ---
#define BM 128
#define BN 128
#define BK 32
#define LDK 40   // padded LDS row (elems); 80B stride, 16B-aligned

__global__ __launch_bounds__(256) void gemm_kernel(
        const unsigned short* __restrict__ Wc,    // [512][512] bf16
        const unsigned short* __restrict__ Cb,    // [20000][512] bf16
        float* __restrict__ out) {                // [512][20000] f32
    __shared__ __align__(16) unsigned short As[BM * LDK];
    __shared__ __align__(16) unsigned short Bs[BN * LDK];

    int tid = threadIdx.x;
    int lane = tid & 63;
    int wid = tid >> 6;
    int wm = wid >> 1, wn = wid & 1;              // 2x2 wave grid, 64x64 each
    int mBase = blockIdx.y * BM;
    int nBase = blockIdx.x * BN;

    f32x4 acc[4][4] = {};

    int srow = tid >> 2;                          // 0..63
    int scol = (tid & 3) * 8;                     // 0,8,16,24

    for (int k0 = 0; k0 < KDIM; k0 += BK) {
        #pragma unroll
        for (int h = 0; h < 2; ++h) {
            int r = srow + h * 64;
            uint4 va = *reinterpret_cast<const uint4*>(
                Wc + (size_t)(mBase + r) * KDIM + k0 + scol);
            *reinterpret_cast<uint4*>(&As[r * LDK + scol]) = va;
            int gb = nBase + r;
            uint4 vb;
            if (gb < NB) vb = *reinterpret_cast<const uint4*>(
                    Cb + (size_t)gb * KDIM + k0 + scol);
            else { vb.x = 0; vb.y = 0; vb.z = 0; vb.w = 0; }
            *reinterpret_cast<uint4*>(&Bs[r * LDK + scol]) = vb;
        }
        __syncthreads();

        int kq = (lane >> 4) * 8;
        int rl = lane & 15;
        bf16x8 af[4], bfr[4];
        #pragma unroll
        for (int i = 0; i < 4; ++i) {
            af[i]  = *reinterpret_cast<const bf16x8*>(&As[(wm * 64 + i * 16 + rl) * LDK + kq]);
            bfr[i] = *reinterpret_cast<const bf16x8*>(&Bs[(wn * 64 + i * 16 + rl) * LDK + kq]);
        }
        #pragma unroll
        for (int i = 0; i < 4; ++i)
            #pragma unroll
            for (int j = 0; j < 4; ++j)
                acc[i][j] = __builtin_amdgcn_mfma_f32_16x16x32_bf16(
                    af[i], bfr[j], acc[i][j], 0, 0, 0);
        __syncthreads();
    }

    int col = lane & 15;
    int rq = (lane >> 4) * 4;
    #pragma unroll
    for (int i = 0; i < 4; ++i) {
        #pragma unroll
        for (int j = 0; j < 4; ++j) {
            int n = nBase + wn * 64 + j * 16 + col;
            if (n < NB) {
                int mRow = mBase + wm * 64 + i * 16 + rq;
                #pragma unroll
                for (int r = 0; r < 4; ++r) {
                    float v = acc[i][j][r];
                    out[(size_t)(mRow + r) * NB + n] = v > 0.f ? v : 0.f;
                }
            }
        }
    }
}

extern "C" void kernel_launch(void* const* d_in, const int* in_sizes, int n_in,
                              void* d_out, int out_size, void* d_ws, size_t ws_size,
                              hipStream_t stream) {
    const int*   nodes = (const int*)d_in[0];
    const int*   neigh = (const int*)d_in[1];
    const float* feat  = (const float*)d_in[2];
    const float* W1    = (const float*)d_in[3];
    const float* W2    = (const float*)d_in[4];
    float* out = (float*)d_out;

    // ws layout: Wc (512KB) | comb (20.48MB)
    const size_t WC_BYTES = (size_t)MDIM * KDIM * 2;
    unsigned short* Wc   = (unsigned short*)d_ws;
    unsigned short* comb = (unsigned short*)((char*)d_ws + WC_BYTES);

    convW_kernel<<<256, 256, 0, stream>>>(W1, W2, Wc);
    agg_kernel<<<NB / 4, 256, 0, stream>>>(nodes, neigh, feat, comb);
    gemm_kernel<<<dim3((NB + BN - 1) / BN, MDIM / BM), 256, 0, stream>>>(Wc, comb, out);
}